// Round 3
// baseline (107.686 us; speedup 1.0000x reference)
//
#include <hip/hip_runtime.h>

#define NN 2048
#define ROWS 32
#define TJ 64                 // j-tile size
#define JT (NN / TJ)          // 32 j-tiles per row
#define IB 8                  // i-values per thread (registers)
#define THREADS 256           // 256*8 = 2048 = full i-range per block
#define GRID (ROWS * JT)      // 1024 blocks -> 4 blocks/CU, 16 waves/CU

static_assert(JT == 32, "block decode uses &31 / >>5");
static_assert(THREADS * IB == NN, "block must cover full i range");

// ws: int ws[0..31] = per-row discordant count over ordered pairs; ws[32] = done ctr
__global__ __launch_bounds__(THREADS) void ktau_count(const float* __restrict__ pred,
                                                      const float* __restrict__ target,
                                                      int* __restrict__ ws,
                                                      float* __restrict__ out) {
    __shared__ float2 jtile[TJ];

    const int blk = blockIdx.x;
    const int row = blk >> 5;
    const int jt  = blk & (JT - 1);
    const float* __restrict__ prow = pred   + row * NN;
    const float* __restrict__ qrow = target + row * NN;
    const int tid = threadIdx.x;

    if (tid < TJ) {
        int j = jt * TJ + tid;
        jtile[tid] = make_float2(prow[j], qrow[j]);
    }

    float pi[IB], qi[IB];
    {
        const float4* p4 = (const float4*)(prow + tid * IB);
        const float4* q4 = (const float4*)(qrow + tid * IB);
        float4 a0 = p4[0], a1 = p4[1];
        float4 b0 = q4[0], b1 = q4[1];
        pi[0]=a0.x; pi[1]=a0.y; pi[2]=a0.z; pi[3]=a0.w;
        pi[4]=a1.x; pi[5]=a1.y; pi[6]=a1.z; pi[7]=a1.w;
        qi[0]=b0.x; qi[1]=b0.y; qi[2]=b0.z; qi[3]=b0.w;
        qi[4]=b1.x; qi[5]=b1.y; qi[6]=b1.z; qi[7]=b1.w;
    }
    __syncthreads();

    // discordant(i,j) <=> signbit( (pj-pi) ^bits (qj-qi) ); pure VALU, no vcc/SALU.
    // Diagonal/self pairs give +0^+0 -> sign 0 -> no contribution.
    unsigned acc[4] = {0u, 0u, 0u, 0u};
    #pragma unroll 8
    for (int jj = 0; jj < TJ; ++jj) {
        float2 pq = jtile[jj];
        #pragma unroll
        for (int k = 0; k < IB; ++k) {
            int x = (__float_as_int(pq.x - pi[k]) ^ __float_as_int(pq.y - qi[k]));
            acc[k & 3] += ((unsigned)x) >> 31;
        }
    }
    int disc = (int)(acc[0] + acc[1] + acc[2] + acc[3]);

    #pragma unroll
    for (int off = 32; off > 0; off >>= 1)
        disc += __shfl_down(disc, off, 64);
    if ((tid & 63) == 0)
        atomicAdd(&ws[row], disc);

    __syncthreads();
    if (tid == 0) {
        __threadfence();
        int old = atomicAdd(&ws[ROWS], 1);
        if (old == GRID - 1) {
            // disc_r counts ordered pairs = 2*disc_unordered;
            // loss_r = 2*disc_u / (N(N-1)/2) = disc_r / T
            const float invT = 1.0f / (float)(((long long)NN * (NN - 1)) / 2);
            float accf = 0.0f;
            for (int r = 0; r < ROWS; ++r) {
                int dr = atomicAdd(&ws[r], 0);   // device-scope coherent read
                accf += (float)dr * invT;
            }
            out[0] = accf / (float)ROWS;
        }
    }
}

extern "C" void kernel_launch(void* const* d_in, const int* in_sizes, int n_in,
                              void* d_out, int out_size, void* d_ws, size_t ws_size,
                              hipStream_t stream) {
    const float* pred   = (const float*)d_in[0];
    const float* target = (const float*)d_in[1];
    float* out = (float*)d_out;
    int* ws    = (int*)d_ws;

    hipMemsetAsync(ws, 0, (ROWS + 1) * sizeof(int), stream);
    ktau_count<<<GRID, THREADS, 0, stream>>>(pred, target, ws, out);
}

// Round 4
// 71.238 us; speedup vs baseline: 1.5116x; 1.5116x over previous
//
#include <hip/hip_runtime.h>

#define NN 2048
#define ROWS 32
#define TJ 128                // j-tile size
#define JT (NN / TJ)          // 16 j-tiles per row
#define IB 8                  // i-values per thread (registers)
#define THREADS 256           // 256*8 = 2048 = full i-range per block
#define GRID (ROWS * JT)      // 512 blocks, 2/CU

static_assert(JT == 16, "block decode uses &15 / >>4");
static_assert(THREADS * IB == NN, "block must cover full i range");

// Kernel A: zero atomics, zero fences. Partial discordant count -> ws[blk].
__global__ __launch_bounds__(THREADS) void ktau_count(const float* __restrict__ pred,
                                                      const float* __restrict__ target,
                                                      int* __restrict__ ws) {
    __shared__ float2 jtile[TJ];
    __shared__ int wpart[THREADS / 64];

    const int blk = blockIdx.x;
    const int row = blk >> 4;
    const int jt  = blk & (JT - 1);
    const float* __restrict__ prow = pred   + row * NN;
    const float* __restrict__ qrow = target + row * NN;
    const int tid = threadIdx.x;

    if (tid < TJ) {
        int j = jt * TJ + tid;
        jtile[tid] = make_float2(prow[j], qrow[j]);
    }

    float pi[IB], qi[IB];
    {
        const float4* p4 = (const float4*)(prow + tid * IB);
        const float4* q4 = (const float4*)(qrow + tid * IB);
        float4 a0 = p4[0], a1 = p4[1];
        float4 b0 = q4[0], b1 = q4[1];
        pi[0]=a0.x; pi[1]=a0.y; pi[2]=a0.z; pi[3]=a0.w;
        pi[4]=a1.x; pi[5]=a1.y; pi[6]=a1.z; pi[7]=a1.w;
        qi[0]=b0.x; qi[1]=b0.y; qi[2]=b0.z; qi[3]=b0.w;
        qi[4]=b1.x; qi[5]=b1.y; qi[6]=b1.z; qi[7]=b1.w;
    }
    __syncthreads();

    // discordant(i,j) <=> signbit( (pj-pi) ^bits (qj-qi) ); pure VALU, no vcc/SALU.
    // Self-pairs: +0 ^ +0 -> sign 0 -> no contribution. Ordered pairs (double count).
    unsigned acc[4] = {0u, 0u, 0u, 0u};
    #pragma unroll 8
    for (int jj = 0; jj < TJ; ++jj) {
        float2 pq = jtile[jj];
        #pragma unroll
        for (int k = 0; k < IB; ++k) {
            int x = (__float_as_int(pq.x - pi[k]) ^ __float_as_int(pq.y - qi[k]));
            acc[k & 3] += ((unsigned)x) >> 31;
        }
    }
    int disc = (int)(acc[0] + acc[1] + acc[2] + acc[3]);

    #pragma unroll
    for (int off = 32; off > 0; off >>= 1)
        disc += __shfl_down(disc, off, 64);
    if ((tid & 63) == 0)
        wpart[tid >> 6] = disc;
    __syncthreads();
    if (tid == 0)
        ws[blk] = wpart[0] + wpart[1] + wpart[2] + wpart[3];   // plain store
}

// Kernel B: reduce 512 partials. loss = (sum of ordered discordants) * invT / ROWS
__global__ __launch_bounds__(256) void ktau_final(const int* __restrict__ ws,
                                                  float* __restrict__ out) {
    __shared__ int wpart[4];
    const int tid = threadIdx.x;
    int v = ws[tid] + ws[tid + 256];
    #pragma unroll
    for (int off = 32; off > 0; off >>= 1)
        v += __shfl_down(v, off, 64);
    if ((tid & 63) == 0) wpart[tid >> 6] = v;
    __syncthreads();
    if (tid == 0) {
        const float invT = 1.0f / (float)(((long long)NN * (NN - 1)) / 2);
        int total = wpart[0] + wpart[1] + wpart[2] + wpart[3];
        out[0] = (float)total * invT / (float)ROWS;
    }
}

extern "C" void kernel_launch(void* const* d_in, const int* in_sizes, int n_in,
                              void* d_out, int out_size, void* d_ws, size_t ws_size,
                              hipStream_t stream) {
    const float* pred   = (const float*)d_in[0];
    const float* target = (const float*)d_in[1];
    float* out = (float*)d_out;
    int* ws    = (int*)d_ws;

    ktau_count<<<GRID, THREADS, 0, stream>>>(pred, target, ws);
    ktau_final<<<1, 256, 0, stream>>>(ws, out);
}

// Round 5
// 69.368 us; speedup vs baseline: 1.5524x; 1.0270x over previous
//
#include <hip/hip_runtime.h>

#define NN 2048
#define ROWS 32
#define TJ 64                 // j-tile size
#define JT (NN / TJ)          // 32 j-tiles per row
#define IB 8                  // i-values per thread (registers)
#define THREADS 256           // 256*8 = 2048 = full i-range per block
#define GRID (ROWS * JT)      // 1024 blocks, 4/CU, 4 waves/SIMD

static_assert(JT == 32, "block decode uses &31 / >>5");
static_assert(THREADS * IB == NN, "block must cover full i range");

typedef float v2f __attribute__((ext_vector_type(2)));

// Kernel A: zero atomics, zero fences. Partial discordant count -> ws[blk].
__global__ __launch_bounds__(THREADS) void ktau_count(const float* __restrict__ pred,
                                                      const float* __restrict__ target,
                                                      int* __restrict__ ws) {
    __shared__ v2f jtile[TJ];
    __shared__ int wpart[THREADS / 64];

    const int blk = blockIdx.x;
    const int row = blk >> 5;
    const int jt  = blk & (JT - 1);
    const float* __restrict__ prow = pred   + row * NN;
    const float* __restrict__ qrow = target + row * NN;
    const int tid = threadIdx.x;

    if (tid < TJ) {
        int j = jt * TJ + tid;
        v2f v; v.x = prow[j]; v.y = qrow[j];
        jtile[tid] = v;
    }

    // register-block 8 (p,q) pairs per thread, packed for v_pk_add_f32
    v2f pq[IB];
    {
        const float4* p4 = (const float4*)(prow + tid * IB);
        const float4* q4 = (const float4*)(qrow + tid * IB);
        float4 a0 = p4[0], a1 = p4[1];
        float4 b0 = q4[0], b1 = q4[1];
        pq[0].x=a0.x; pq[0].y=b0.x;  pq[1].x=a0.y; pq[1].y=b0.y;
        pq[2].x=a0.z; pq[2].y=b0.z;  pq[3].x=a0.w; pq[3].y=b0.w;
        pq[4].x=a1.x; pq[4].y=b1.x;  pq[5].x=a1.y; pq[5].y=b1.y;
        pq[6].x=a1.z; pq[6].y=b1.z;  pq[7].x=a1.w; pq[7].y=b1.w;
    }
    __syncthreads();

    // discordant(i,j) <=> signbit( (pj-pi) ^bits (qj-qi) )
    // packed: d = pqj - pqi in ONE v_pk_add_f32; then xor halves, count sign.
    // Self pairs: +0 ^ +0 -> 0, no contribution. Ordered pairs (double count).
    unsigned acc[4] = {0u, 0u, 0u, 0u};
    #pragma unroll 8
    for (int jj = 0; jj < TJ; ++jj) {
        v2f pqj = jtile[jj];
        #pragma unroll
        for (int k = 0; k < IB; ++k) {
            v2f d = pqj - pq[k];
            int x = (__float_as_int(d.x) ^ __float_as_int(d.y));
            acc[k & 3] += ((unsigned)x) >> 31;
        }
    }
    int disc = (int)(acc[0] + acc[1] + acc[2] + acc[3]);

    #pragma unroll
    for (int off = 32; off > 0; off >>= 1)
        disc += __shfl_down(disc, off, 64);
    if ((tid & 63) == 0)
        wpart[tid >> 6] = disc;
    __syncthreads();
    if (tid == 0)
        ws[blk] = wpart[0] + wpart[1] + wpart[2] + wpart[3];   // plain store
}

// Kernel B: reduce GRID partials. loss = (sum of ordered discordants)*invT/ROWS
__global__ __launch_bounds__(256) void ktau_final(const int* __restrict__ ws,
                                                  float* __restrict__ out) {
    __shared__ int wpart[4];
    const int tid = threadIdx.x;
    int v = 0;
    #pragma unroll
    for (int b = tid; b < GRID; b += 256) v += ws[b];
    #pragma unroll
    for (int off = 32; off > 0; off >>= 1)
        v += __shfl_down(v, off, 64);
    if ((tid & 63) == 0) wpart[tid >> 6] = v;
    __syncthreads();
    if (tid == 0) {
        const float invT = 1.0f / (float)(((long long)NN * (NN - 1)) / 2);
        int total = wpart[0] + wpart[1] + wpart[2] + wpart[3];
        out[0] = (float)total * invT / (float)ROWS;
    }
}

extern "C" void kernel_launch(void* const* d_in, const int* in_sizes, int n_in,
                              void* d_out, int out_size, void* d_ws, size_t ws_size,
                              hipStream_t stream) {
    const float* pred   = (const float*)d_in[0];
    const float* target = (const float*)d_in[1];
    float* out = (float*)d_out;
    int* ws    = (int*)d_ws;

    ktau_count<<<GRID, THREADS, 0, stream>>>(pred, target, ws);
    ktau_final<<<1, 256, 0, stream>>>(ws, out);
}

// Round 6
// 68.154 us; speedup vs baseline: 1.5801x; 1.0178x over previous
//
#include <hip/hip_runtime.h>

#define NN 2048
#define ROWS 32
#define TS 128                 // tile size
#define NT (NN / TS)           // 16 tiles per row
#define NPAIR (NT * (NT + 1) / 2)   // 136 tile-pairs (ta <= tb)
#define GRID (ROWS * NPAIR)    // 4352 blocks of 64 threads
#define THREADS 64

typedef float v2f __attribute__((ext_vector_type(2)));

// Each block: row r, tile pair (ta <= tb). Thread owns 2 consecutive i in tile ta;
// j iterates over tile tb from LDS broadcast. discordant(i,j) <=> signbit(dp ^ dq).
// Off-diagonal blocks count each unordered cross pair once -> weight 2.
// Diagonal blocks count the full rect (= ordered pairs; self-pairs contribute 0) -> weight 1.
__global__ __launch_bounds__(THREADS) void ktau_count(const float* __restrict__ pred,
                                                      const float* __restrict__ target,
                                                      int* __restrict__ ws) {
    __shared__ v2f jtile[TS];

    const int blk = blockIdx.x;
    const int row = blk / NPAIR;
    int t = blk - row * NPAIR;
    // decode t -> (ta, tb), ta <= tb; row ta has (NT - ta) entries
    int ta = 0, base = 0;
    while (t >= base + (NT - ta)) { base += NT - ta; ++ta; }
    const int tb = ta + (t - base);

    const float* __restrict__ prow = pred   + row * NN;
    const float* __restrict__ qrow = target + row * NN;
    const int tid = threadIdx.x;

    // stage j-tile (2 elements per thread)
    #pragma unroll
    for (int t2 = tid; t2 < TS; t2 += THREADS) {
        int j = tb * TS + t2;
        v2f v; v.x = prow[j]; v.y = qrow[j];
        jtile[t2] = v;
    }

    // i-side: 2 consecutive i per thread (8B-aligned float2 loads)
    const int i0 = ta * TS + tid * 2;
    float2 pp = *(const float2*)(prow + i0);
    float2 qq = *(const float2*)(qrow + i0);
    v2f pq0; pq0.x = pp.x; pq0.y = qq.x;
    v2f pq1; pq1.x = pp.y; pq1.y = qq.y;
    __syncthreads();

    // 3 VALU/pair: v_pk_add_f32 (sub), v_xor_b32, v_alignbit_b32 (shift-in sign bit);
    // popcount flush every 32 j's via v_bcnt_u32_b32.
    unsigned disc = 0;
    for (int h = 0; h < TS / 32; ++h) {
        unsigned b0 = 0, b1 = 0;
        #pragma unroll
        for (int jj = 0; jj < 32; ++jj) {
            v2f pqj = jtile[h * 32 + jj];
            v2f d0 = pqj - pq0;
            v2f d1 = pqj - pq1;
            unsigned x0 = (unsigned)(__float_as_int(d0.x) ^ __float_as_int(d0.y));
            unsigned x1 = (unsigned)(__float_as_int(d1.x) ^ __float_as_int(d1.y));
            b0 = __builtin_amdgcn_alignbit(b0, x0, 31);
            b1 = __builtin_amdgcn_alignbit(b1, x1, 31);
        }
        disc += __builtin_popcount(b0) + __builtin_popcount(b1);
    }

    int d = (int)disc;
    #pragma unroll
    for (int off = 32; off > 0; off >>= 1)
        d += __shfl_down(d, off, 64);
    if (tid == 0)
        ws[blk] = (ta == tb) ? d : (d << 1);   // plain store, weighted
}

// Reduce GRID weighted partials. loss = (ordered discordant total) * invT / ROWS
__global__ __launch_bounds__(256) void ktau_final(const int* __restrict__ ws,
                                                  float* __restrict__ out) {
    __shared__ int wpart[4];
    const int tid = threadIdx.x;
    int v = 0;
    for (int b = tid; b < GRID; b += 256) v += ws[b];
    #pragma unroll
    for (int off = 32; off > 0; off >>= 1)
        v += __shfl_down(v, off, 64);
    if ((tid & 63) == 0) wpart[tid >> 6] = v;
    __syncthreads();
    if (tid == 0) {
        const float invT = 1.0f / (float)(((long long)NN * (NN - 1)) / 2);
        int total = wpart[0] + wpart[1] + wpart[2] + wpart[3];
        out[0] = (float)total * invT / (float)ROWS;
    }
}

extern "C" void kernel_launch(void* const* d_in, const int* in_sizes, int n_in,
                              void* d_out, int out_size, void* d_ws, size_t ws_size,
                              hipStream_t stream) {
    const float* pred   = (const float*)d_in[0];
    const float* target = (const float*)d_in[1];
    float* out = (float*)d_out;
    int* ws    = (int*)d_ws;

    ktau_count<<<GRID, THREADS, 0, stream>>>(pred, target, ws);
    ktau_final<<<1, 256, 0, stream>>>(ws, out);
}